// Round 1
// baseline (1739.314 us; speedup 1.0000x reference)
//
#include <hip/hip_runtime.h>

// LSA fused attention: out = softmax(QK^T/temp, diag=-inf) @ V
// B=64, N=1024, D=768, fp32 in/out, bf16 MFMA compute.
//
// Block = 512 threads (8 waves), one (batch, 64-row q-tile) per block.
// Tiles: BM=64 q rows, BKV=128 kv cols/tile (8 tiles), D chunked by 128 (6 chunks).
// Waves: (mr = w&1) -> 32-q-row group; (nc = w>>1) -> 32-wide kv group (QK) and
//        32-wide d group within each 128-d chunk (PV).
// MFMA v_mfma_f32_32x32x16_bf16:
//   A: lane row = l&31, k = 8*(l>>5)+j ; B: lane col = l&31, same k
//   C/D: col = l&31, row = (reg&3) + 8*(reg>>2) + 4*(l>>5)   [m74/m101]

typedef __bf16 bf16x8 __attribute__((ext_vector_type(8)));
typedef float  f32x16 __attribute__((ext_vector_type(16)));
typedef float  f32x4v __attribute__((ext_vector_type(4)));
typedef unsigned short u16x4 __attribute__((ext_vector_type(4)));

#define QS_STRIDE 776   // 768 + 8 pad (16B-aligned rows, conflict-spread)
#define KS_STRIDE 136   // 128 + 8 pad
#define PS_STRIDE 136

#define OFF_KV  99328              // 64*776*2
#define OFF_PS  (OFF_KV + 34816)   // 128*136*2
#define OFF_RM  (OFF_PS + 17408)   // 64*136*2
#define OFF_RL  (OFF_RM + 1024)
#define LDS_BYTES (OFF_RL + 1024)  // 153600

__device__ __forceinline__ unsigned short f2bf(float x) {
    unsigned int b = __builtin_bit_cast(unsigned int, x);
    b += 0x7FFFu + ((b >> 16) & 1u);   // round-to-nearest-even
    return (unsigned short)(b >> 16);
}

__global__ __launch_bounds__(512) void lsa_fused(
    const float* __restrict__ Qg, const float* __restrict__ Kg,
    const float* __restrict__ Vg, const float* __restrict__ Tg,
    float* __restrict__ Og)
{
    extern __shared__ char smem[];
    unsigned short* Qs  = (unsigned short*)(smem);            // [64][776]
    unsigned short* KVs = (unsigned short*)(smem + OFF_KV);   // [128][136] K-chunk or V^T-chunk
    unsigned short* Ps  = (unsigned short*)(smem + OFF_PS);   // [64][136]
    float* red_m = (float*)(smem + OFF_RM);                   // [64][4]
    float* red_l = (float*)(smem + OFF_RL);                   // [64][4]

    const int tid  = threadIdx.x;
    const int lane = tid & 63;
    const int w    = tid >> 6;
    const int mr   = w & 1;
    const int nc   = w >> 1;
    const int half = lane >> 5;
    const int l31  = lane & 31;

    // XCD-locality swizzle: XCD x gets batches {2x,2x+1} per round (id%8 ~ XCD).
    int id    = blockIdx.x;
    int xcd   = id & 7;
    int jj_   = id >> 3;                                // [0,128)
    int batch = (jj_ >> 5) * 16 + xcd * 2 + ((jj_ >> 4) & 1);
    int qt    = jj_ & 15;

    const float scale = 1.0f / Tg[0];

    // ---- stage Q (scaled, bf16) once: 64 x 768 ----
    {
        const float* qp = Qg + ((size_t)batch * 1024 + (size_t)qt * 64) * 768;
        #pragma unroll
        for (int i = 0; i < 24; ++i) {
            int idx = tid + i * 512;          // [0,12288)
            int row = idx / 192, c4 = idx % 192;
            f32x4v q4 = *(const f32x4v*)(qp + (size_t)row * 768 + c4 * 4);
            u16x4 h = { f2bf(q4[0] * scale), f2bf(q4[1] * scale),
                        f2bf(q4[2] * scale), f2bf(q4[3] * scale) };
            *(u16x4*)(Qs + row * QS_STRIDE + c4 * 4) = h;
        }
    }

    f32x16 acc[6];
    #pragma unroll
    for (int ch = 0; ch < 6; ++ch)
        #pragma unroll
        for (int r = 0; r < 16; ++r) acc[ch][r] = 0.0f;

    float m_st[16], l_st[16];
    #pragma unroll
    for (int r = 0; r < 16; ++r) { m_st[r] = -1e30f; l_st[r] = 0.0f; }

    const unsigned short* qa_base = Qs + (mr * 32 + l31) * QS_STRIDE + 8 * half;
    const unsigned short* kv_base = KVs + (nc * 32 + l31) * KS_STRIDE + 8 * half;
    const unsigned short* pa_base = Ps + (mr * 32 + l31) * PS_STRIDE + 8 * half;
    const int diag_tile = qt >> 1;

    for (int t = 0; t < 8; ++t) {
        const size_t kvbase = ((size_t)batch * 1024 + (size_t)t * 128) * 768;

        // ================= QK^T =================
        f32x16 s;
        #pragma unroll
        for (int r = 0; r < 16; ++r) s[r] = 0.0f;

        for (int ch = 0; ch < 6; ++ch) {
            // stage K chunk 128kv x 128d (entry: KVs free via previous barrier)
            {
                const float* kp = Kg + kvbase + ch * 128;
                #pragma unroll
                for (int i = 0; i < 8; ++i) {
                    int idx = tid + i * 512;         // [0,4096)
                    int row = idx >> 5, c4 = idx & 31;
                    f32x4v k4 = *(const f32x4v*)(kp + (size_t)row * 768 + c4 * 4);
                    u16x4 h = { f2bf(k4[0]), f2bf(k4[1]), f2bf(k4[2]), f2bf(k4[3]) };
                    *(u16x4*)(KVs + row * KS_STRIDE + c4 * 4) = h;
                }
            }
            __syncthreads();
            #pragma unroll
            for (int ks = 0; ks < 8; ++ks) {
                bf16x8 qa = *(const bf16x8*)(qa_base + ch * 128 + ks * 16);
                bf16x8 kb = *(const bf16x8*)(kv_base + ks * 16);
                s = __builtin_amdgcn_mfma_f32_32x32x16_bf16(qa, kb, s, 0, 0, 0);
            }
            __syncthreads();
        }

        // ================= softmax (online) =================
        if (t == diag_tile) {
            int kv_g = t * 128 + nc * 32 + l31;
            #pragma unroll
            for (int r = 0; r < 16; ++r) {
                int q_g = qt * 64 + mr * 32 + (r & 3) + 8 * (r >> 2) + 4 * half;
                if (q_g == kv_g) s[r] = -1e30f;
            }
        }

        // per-wave partial row max over 32 kv cols
        float pm[16];
        #pragma unroll
        for (int r = 0; r < 16; ++r) pm[r] = s[r];
        #pragma unroll
        for (int msk = 1; msk < 32; msk <<= 1) {
            #pragma unroll
            for (int r = 0; r < 16; ++r)
                pm[r] = fmaxf(pm[r], __shfl_xor(pm[r], msk, 64));
        }
        if (l31 == 0) {
            #pragma unroll
            for (int r = 0; r < 16; ++r) {
                int rig = (r & 3) + 8 * (r >> 2) + 4 * half;
                red_m[(mr * 32 + rig) * 4 + nc] = pm[r];
            }
        }
        __syncthreads();

        float mnew[16], cfac[16];
        #pragma unroll
        for (int r = 0; r < 16; ++r) {
            int rig = (r & 3) + 8 * (r >> 2) + 4 * half;
            f32x4v v = *(const f32x4v*)(red_m + (mr * 32 + rig) * 4);
            float mt = fmaxf(fmaxf(v[0], v[1]), fmaxf(v[2], v[3]));
            mnew[r] = fmaxf(m_st[r], mt);
            cfac[r] = __expf(m_st[r] - mnew[r]);
            m_st[r] = mnew[r];
        }
        #pragma unroll
        for (int ch = 0; ch < 6; ++ch)
            #pragma unroll
            for (int r = 0; r < 16; ++r) acc[ch][r] *= cfac[r];

        float pv_[16], pl[16];
        #pragma unroll
        for (int r = 0; r < 16; ++r) { pv_[r] = __expf(s[r] - mnew[r]); pl[r] = pv_[r]; }
        #pragma unroll
        for (int msk = 1; msk < 32; msk <<= 1) {
            #pragma unroll
            for (int r = 0; r < 16; ++r)
                pl[r] += __shfl_xor(pl[r], msk, 64);
        }
        if (l31 == 0) {
            #pragma unroll
            for (int r = 0; r < 16; ++r) {
                int rig = (r & 3) + 8 * (r >> 2) + 4 * half;
                red_l[(mr * 32 + rig) * 4 + nc] = pl[r];
            }
        }
        #pragma unroll
        for (int r = 0; r < 16; ++r) {
            int rig = (r & 3) + 8 * (r >> 2) + 4 * half;
            Ps[(mr * 32 + rig) * PS_STRIDE + nc * 32 + l31] = f2bf(pv_[r]);
        }
        __syncthreads();

        #pragma unroll
        for (int r = 0; r < 16; ++r) {
            int rig = (r & 3) + 8 * (r >> 2) + 4 * half;
            f32x4v v = *(const f32x4v*)(red_l + (mr * 32 + rig) * 4);
            l_st[r] = l_st[r] * cfac[r] + (v[0] + v[1] + v[2] + v[3]);
        }

        // P fragments (A-operand), full 128-kv tile, held across d-chunks
        bf16x8 pa[8];
        #pragma unroll
        for (int ks = 0; ks < 8; ++ks)
            pa[ks] = *(const bf16x8*)(pa_base + ks * 16);

        // ================= P @ V =================
        for (int ch = 0; ch < 6; ++ch) {
            __syncthreads();   // KVs free (prev chunk readers / QK readers done)
            // stage V^T chunk: [128 d][128 kv] via 4x4 register micro-transpose
            #pragma unroll
            for (int i2 = 0; i2 < 2; ++i2) {
                int idx = tid + i2 * 512;        // [0,1024)
                int rg = idx & 31, cg = idx >> 5;
                const float* vp = Vg + kvbase + (size_t)(rg * 4) * 768 + ch * 128 + cg * 4;
                f32x4v a0 = *(const f32x4v*)(vp);
                f32x4v a1 = *(const f32x4v*)(vp + 768);
                f32x4v a2 = *(const f32x4v*)(vp + 1536);
                f32x4v a3 = *(const f32x4v*)(vp + 2304);
                #pragma unroll
                for (int q4 = 0; q4 < 4; ++q4) {
                    u16x4 h = { f2bf(a0[q4]), f2bf(a1[q4]), f2bf(a2[q4]), f2bf(a3[q4]) };
                    *(u16x4*)(KVs + (cg * 4 + q4) * KS_STRIDE + rg * 4) = h;
                }
            }
            __syncthreads();
            #pragma unroll
            for (int ks = 0; ks < 8; ++ks) {
                bf16x8 vb = *(const bf16x8*)(kv_base + ks * 16);
                acc[ch] = __builtin_amdgcn_mfma_f32_32x32x16_bf16(pa[ks], vb, acc[ch], 0, 0, 0);
            }
        }
        __syncthreads();   // KVs free before next tile's K staging
    }

    // ================= epilogue: O / l =================
    float rinv[16];
    #pragma unroll
    for (int r = 0; r < 16; ++r) rinv[r] = 1.0f / l_st[r];

    size_t obase = ((size_t)batch * 1024 + (size_t)qt * 64 + mr * 32) * 768 + nc * 32 + l31;
    #pragma unroll
    for (int r = 0; r < 16; ++r) {
        int rig = (r & 3) + 8 * (r >> 2) + 4 * half;
        float* op = Og + obase + (size_t)rig * 768;
        #pragma unroll
        for (int ch = 0; ch < 6; ++ch)
            op[ch * 128] = acc[ch][r] * rinv[r];
    }
}

extern "C" void kernel_launch(void* const* d_in, const int* in_sizes, int n_in,
                              void* d_out, int out_size, void* d_ws, size_t ws_size,
                              hipStream_t stream) {
    (void)in_sizes; (void)n_in; (void)d_ws; (void)ws_size; (void)out_size;
    const float* Q = (const float*)d_in[0];
    const float* K = (const float*)d_in[1];
    const float* V = (const float*)d_in[2];
    const float* T = (const float*)d_in[3];
    float* O = (float*)d_out;
    lsa_fused<<<dim3(1024), dim3(512), LDS_BYTES, stream>>>(Q, K, V, T, O);
}

// Round 2
// 1549.212 us; speedup vs baseline: 1.1227x; 1.1227x over previous
//
#include <hip/hip_runtime.h>

// LSA fused attention: out = softmax(QK^T/temp, diag=-inf) @ V
// B=64, N=1024, D=768, fp32 I/O, bf16 MFMA (32x32x16).
//
// SWAPPED layout: S^T = mfma(A=K, B=Q)  ->  lane owns one q column.
//   A-frag: row=l&31 (kv), k=8*(l>>5)+j ; B-frag: col=l&31 (q), same k
//   C/D: col=l&31 (q), row=(r&3)+8*(r>>2)+4*(l>>5) (kv / d)
// PV: O^T = mfma(A=V^T, B=P^T): P^T frag is lane-local after softmax.
// K is loaded DIRECTLY global->reg (sharing factor only 2) -> QK barrier-free.
// Q, V^T, P staged in LDS with 16B XOR swizzle (^(row&15)<<4) -> conflict-free.
// V staging is async-split: issue loads before MFMAs, write LDS after barrier.

typedef __bf16 bf16x8 __attribute__((ext_vector_type(8)));
typedef __bf16 bf16x4 __attribute__((ext_vector_type(4)));
typedef float  f32x16 __attribute__((ext_vector_type(16)));
typedef float  f32x4v __attribute__((ext_vector_type(4)));

#define OFF_V  98304               // Qs: [64][768] bf16, stride 1536B, swizzled
#define OFF_P  131072              // Vs: [128 d][128 kv] bf16, stride 256B, swizzled
#define OFF_RM 147456              // Ps: [64 q][128 kv] bf16, stride 256B, swizzled
#define OFF_RL 148480
#define LDS_BYTES 149504           // 146 KB

__device__ __forceinline__ void stage_load(f32x4v (&vr)[2][4], const float* __restrict__ Vg,
                                           size_t kvbase, int srg, int scg, int ch) {
    #pragma unroll
    for (int i2 = 0; i2 < 2; ++i2) {
        const float* vp = Vg + kvbase + (size_t)(srg * 4) * 768 + ch * 128 + (scg + i2 * 16) * 4;
        #pragma unroll
        for (int rr = 0; rr < 4; ++rr)
            vr[i2][rr] = *(const f32x4v*)(vp + (size_t)rr * 768);
    }
}

__device__ __forceinline__ void stage_write(const f32x4v (&vr)[2][4], char* Vb, int srg, int scg) {
    #pragma unroll
    for (int i2 = 0; i2 < 2; ++i2) {
        int cg = scg + i2 * 16;
        #pragma unroll
        for (int q4 = 0; q4 < 4; ++q4) {
            int drow = cg * 4 + q4;
            bf16x4 hv = { (__bf16)vr[i2][0][q4], (__bf16)vr[i2][1][q4],
                          (__bf16)vr[i2][2][q4], (__bf16)vr[i2][3][q4] };
            *(bf16x4*)(Vb + drow * 256 + ((srg * 8) ^ ((drow & 15) << 4))) = hv;
        }
    }
}

__global__ __launch_bounds__(512) void lsa_fused(
    const float* __restrict__ Qg, const float* __restrict__ Kg,
    const float* __restrict__ Vg, const float* __restrict__ Tg,
    float* __restrict__ Og)
{
    extern __shared__ char smem[];
    char*  Qb    = smem;                      // [64 q][768 d] bf16, swizzled
    char*  Vb    = smem + OFF_V;              // [128 d][128 kv] bf16, swizzled
    char*  Pb    = smem + OFF_P;              // [64 q][128 kv] bf16, swizzled
    float* red_m = (float*)(smem + OFF_RM);   // [64][4]
    float* red_l = (float*)(smem + OFF_RL);   // [64][4]

    const int tid  = threadIdx.x;
    const int lane = tid & 63;
    const int w    = tid >> 6;
    const int mr   = w & 1;        // q group (32 rows)
    const int nc   = w >> 1;       // kv group (QK) / d group (PV)
    const int half = lane >> 5;
    const int l31  = lane & 31;

    // XCD-locality swizzle: XCD x serves batches {2x,2x+1} per round.
    int id    = blockIdx.x;
    int xcd   = id & 7;
    int jj    = id >> 3;
    int batch = (jj >> 5) * 16 + xcd * 2 + ((jj >> 4) & 1);
    int qt    = jj & 15;

    // fold log2(e) into the Q scale -> softmax in exp2 domain (v_exp_f32 native)
    const float scale2 = 1.4426950408889634f / Tg[0];

    // ---- stage Q once: 64 x 768 fp32 -> bf16 swizzled ----
    {
        const float* qp   = Qg + ((size_t)batch * 1024 + (size_t)qt * 64) * 768;
        int   row   = tid >> 3, c0 = tid & 7;
        const float* qrow = qp + (size_t)row * 768;
        char* qdst  = Qb + row * 1536;
        int   rx    = (row & 15) << 4;
        #pragma unroll
        for (int j = 0; j < 24; ++j) {
            int c4 = c0 + j * 8;
            f32x4v q4 = *(const f32x4v*)(qrow + c4 * 4);
            bf16x4 hq = { (__bf16)(q4[0] * scale2), (__bf16)(q4[1] * scale2),
                          (__bf16)(q4[2] * scale2), (__bf16)(q4[3] * scale2) };
            *(bf16x4*)(qdst + ((c4 * 8) ^ rx)) = hq;
        }
    }
    __syncthreads();

    f32x16 acc[6];
    #pragma unroll
    for (int ch = 0; ch < 6; ++ch)
        #pragma unroll
        for (int r = 0; r < 16; ++r) acc[ch][r] = 0.0f;
    float m_st = -1e30f, l_st = 0.0f;

    const int    qrow_g = mr * 32 + l31;                 // this lane's q row (local)
    const int    qglob  = qt * 64 + qrow_g;              // q row within batch
    char*        qfbase = Qb + qrow_g * 1536;
    const int    qx     = (qrow_g & 15) << 4;
    char*        pfbase = Pb + qrow_g * 256;
    const int    vrow   = nc * 32 + l31;                 // V^T d-row for A-frag
    char*        vfbase = Vb + vrow * 256;
    const int    vx     = (vrow & 15) << 4;
    const int    diag_tile = qt >> 1;
    const int    srg = tid & 31, scg = tid >> 5;         // V staging mapping

    #pragma unroll 1
    for (int t = 0; t < 8; ++t) {
        const size_t kvbase = ((size_t)batch * 1024 + (size_t)t * 128) * 768;

        // ================= QK^T (barrier-free) =================
        f32x16 s;
        #pragma unroll
        for (int r = 0; r < 16; ++r) s[r] = 0.0f;

        const float* kptr = Kg + kvbase + (size_t)(nc * 32 + l31) * 768 + 8 * half;
        #pragma unroll
        for (int ch = 0; ch < 6; ++ch) {
            #pragma unroll
            for (int ks = 0; ks < 8; ++ks) {
                f32x4v k0 = *(const f32x4v*)(kptr + ch * 128 + ks * 16);
                f32x4v k1 = *(const f32x4v*)(kptr + ch * 128 + ks * 16 + 4);
                bf16x8 kf = { (__bf16)k0[0], (__bf16)k0[1], (__bf16)k0[2], (__bf16)k0[3],
                              (__bf16)k1[0], (__bf16)k1[1], (__bf16)k1[2], (__bf16)k1[3] };
                bf16x8 qf = *(const bf16x8*)(qfbase + ((ch * 256 + ks * 32 + half * 16) ^ qx));
                s = __builtin_amdgcn_mfma_f32_32x32x16_bf16(kf, qf, s, 0, 0, 0);
            }
        }

        // diagonal self-exclusion (only the tile containing the diagonal)
        if (t == diag_tile) {
            #pragma unroll
            for (int r = 0; r < 16; ++r) {
                int kvg = t * 128 + nc * 32 + (r & 3) + 8 * (r >> 2) + 4 * half;
                if (kvg == qglob) s[r] = -1e30f;
            }
        }

        // V chunk 0 loads: latency hides under softmax
        f32x4v vr[2][4];
        stage_load(vr, Vg, kvbase, srg, scg, 0);

        // ================= online softmax (lane-local q) =================
        float pm = s[0];
        #pragma unroll
        for (int r = 1; r < 16; ++r) pm = fmaxf(pm, s[r]);
        pm = fmaxf(pm, __shfl_xor(pm, 32, 64));
        if (half == 0) red_m[qrow_g * 4 + nc] = pm;
        __syncthreads();                                   // bar1
        f32x4v m4 = *(const f32x4v*)(red_m + qrow_g * 4);
        float mnew = fmaxf(fmaxf(m4[0], m4[1]), fmaxf(m4[2], m4[3]));
        mnew = fmaxf(mnew, m_st);
        float cf = exp2f(m_st - mnew);
        m_st = mnew;

        float pl = 0.0f;
        #pragma unroll
        for (int r = 0; r < 16; ++r) { s[r] = exp2f(s[r] - mnew); pl += s[r]; }
        pl += __shfl_xor(pl, 32, 64);
        l_st = l_st * cf + pl;

        #pragma unroll
        for (int ch = 0; ch < 6; ++ch)
            #pragma unroll
            for (int r = 0; r < 16; ++r) acc[ch][r] *= cf;

        // pack P row (bf16) into Ps: kv groups {0-3,8-11,16-19,24-27}+4h
        #pragma unroll
        for (int g = 0; g < 4; ++g) {
            bf16x4 hp = { (__bf16)s[4*g+0], (__bf16)s[4*g+1],
                          (__bf16)s[4*g+2], (__bf16)s[4*g+3] };
            *(bf16x4*)(pfbase + ((nc * 64 + g * 16 + half * 8) ^ qx)) = hp;
        }
        stage_write(vr, Vb, srg, scg);                     // V chunk 0 -> LDS
        __syncthreads();                                   // bar2

        // P^T fragments: full 128-kv row for this lane's q (reused all 6 chunks)
        bf16x8 pa[8];
        #pragma unroll
        for (int ks = 0; ks < 8; ++ks)
            pa[ks] = *(const bf16x8*)(pfbase + ((ks * 32 + half * 16) ^ qx));

        // ================= P @ V (async-split V staging) =================
        #pragma unroll
        for (int ch = 0; ch < 6; ++ch) {
            if (ch < 5) stage_load(vr, Vg, kvbase, srg, scg, ch + 1);
            #pragma unroll
            for (int ks = 0; ks < 8; ++ks) {
                bf16x8 vf = *(const bf16x8*)(vfbase + ((ks * 32 + half * 16) ^ vx));
                acc[ch] = __builtin_amdgcn_mfma_f32_32x32x16_bf16(vf, pa[ks], acc[ch], 0, 0, 0);
            }
            if (ch < 5) {
                __syncthreads();
                stage_write(vr, Vb, srg, scg);
                __syncthreads();
            }
        }
    }

    // ================= epilogue =================
    if (half == 0) red_l[qrow_g * 4 + nc] = l_st;
    __syncthreads();
    f32x4v l4 = *(const f32x4v*)(red_l + qrow_g * 4);
    float rinv = 1.0f / (l4[0] + l4[1] + l4[2] + l4[3]);

    float* op = Og + ((size_t)batch * 1024 + (size_t)qglob) * 768;
    #pragma unroll
    for (int ch = 0; ch < 6; ++ch)
        #pragma unroll
        for (int g = 0; g < 4; ++g) {
            f32x4v o4 = { acc[ch][4*g+0] * rinv, acc[ch][4*g+1] * rinv,
                          acc[ch][4*g+2] * rinv, acc[ch][4*g+3] * rinv };
            *(f32x4v*)(op + ch * 128 + nc * 32 + g * 8 + half * 4) = o4;
        }
}

extern "C" void kernel_launch(void* const* d_in, const int* in_sizes, int n_in,
                              void* d_out, int out_size, void* d_ws, size_t ws_size,
                              hipStream_t stream) {
    (void)in_sizes; (void)n_in; (void)d_ws; (void)ws_size; (void)out_size;
    const float* Q = (const float*)d_in[0];
    const float* K = (const float*)d_in[1];
    const float* V = (const float*)d_in[2];
    const float* T = (const float*)d_in[3];
    float* O = (float*)d_out;
    lsa_fused<<<dim3(1024), dim3(512), LDS_BYTES, stream>>>(Q, K, V, T, O);
}